// Round 9
// baseline (1272.956 us; speedup 1.0000x reference)
//
#include <hip/hip_runtime.h>
#include <hip/hip_fp16.h>
#include <math.h>

#define NN 100000
#define ICH 128
#define OCH 40
#define NE 3200000
#define NB 196                         // buckets of 512 nodes: bucket = dst >> 9
#define CAP 20480                      // per-bucket capacity (mean 16384, sigma ~128)
#define TILE 4096
#define NBIN ((NE + TILE - 1) / TILE)  // 782
#define YSTRIDE 64                     // fp8 row: 40 B data + 24 B pad = exactly 1 cache line

typedef __attribute__((ext_vector_type(2))) float floatx2;

// decode 8 fp8 (uint2) -> acc[8] +=
__device__ __forceinline__ void acc_fp8x8(const uint2 u, float* acc) {
    floatx2 p0 = __builtin_amdgcn_cvt_pk_f32_fp8((int)u.x, false);
    floatx2 p1 = __builtin_amdgcn_cvt_pk_f32_fp8((int)u.x, true);
    floatx2 p2 = __builtin_amdgcn_cvt_pk_f32_fp8((int)u.y, false);
    floatx2 p3 = __builtin_amdgcn_cvt_pk_f32_fp8((int)u.y, true);
    acc[0] += p0.x; acc[1] += p0.y; acc[2] += p1.x; acc[3] += p1.y;
    acc[4] += p2.x; acc[5] += p2.y; acc[6] += p3.x; acc[7] += p3.y;
}

// encode 8 f32 -> uint2 of fp8
__device__ __forceinline__ uint2 pack_fp8x8(const float* v) {
    int lo = 0, hi = 0;
    lo = __builtin_amdgcn_cvt_pk_fp8_f32(v[0], v[1], lo, false);
    lo = __builtin_amdgcn_cvt_pk_fp8_f32(v[2], v[3], lo, true);
    hi = __builtin_amdgcn_cvt_pk_fp8_f32(v[4], v[5], hi, false);
    hi = __builtin_amdgcn_cvt_pk_fp8_f32(v[6], v[7], hi, true);
    return make_uint2((unsigned int)lo, (unsigned int)hi);
}

// ---- phase 1: bin edges by dst-bucket; dense packed writes per bucket ----
__global__ __launch_bounds__(256) void k_bin(const int* __restrict__ ei, int* __restrict__ bcursor,
                                             unsigned int* __restrict__ packed) {
    __shared__ unsigned int entries[TILE];
    __shared__ unsigned char bid[TILE];
    __shared__ int hist[256], base[256], gbase[256], cur[256];
    int t = threadIdx.x;
    int tile0 = blockIdx.x * TILE;
    int tcnt = min(TILE, NE - tile0);
    hist[t] = 0;
    __syncthreads();
    int src[16], dst[16];
#pragma unroll
    for (int i = 0; i < 16; ++i) {
        int l = t + i * 256;
        if (l < tcnt) {
            int e = tile0 + l;
            src[i] = ei[e];
            dst[i] = ei[NE + e];
            atomicAdd(&hist[dst[i] >> 9], 1);
        } else dst[i] = -1;
    }
    __syncthreads();
    int own = hist[t];
    base[t] = own;
    __syncthreads();
    for (int off = 1; off < 256; off <<= 1) {
        int v = (t >= off) ? base[t - off] : 0;
        __syncthreads();
        base[t] += v;
        __syncthreads();
    }
    int excl = base[t] - own;
    __syncthreads();
    base[t] = excl;
    cur[t] = excl;
    if (t < NB && own > 0) gbase[t] = atomicAdd(&bcursor[t], own);
    __syncthreads();
#pragma unroll
    for (int i = 0; i < 16; ++i) {
        if (dst[i] >= 0) {
            int b = dst[i] >> 9;
            int pos = atomicAdd(&cur[b], 1);
            entries[pos] = ((unsigned int)(dst[i] & 511) << 17) | (unsigned int)src[i];
            bid[pos] = (unsigned char)b;
        }
    }
    __syncthreads();
    for (int l = t; l < tcnt; l += 256) {
        int b = bid[l];
        packed[(size_t)b * CAP + gbase[b] + (l - base[b])] = entries[l];
    }
}

// ---- phase 2: scan bucket counts -> bucket CSR bases ----
__global__ __launch_bounds__(256) void k_bscan(const int* __restrict__ bcursor, int* __restrict__ bbase,
                                               int* __restrict__ rowptr) {
    __shared__ int s[256];
    int t = threadIdx.x;
    int v = (t < NB) ? bcursor[t] : 0;
    s[t] = v;
    __syncthreads();
    for (int off = 1; off < 256; off <<= 1) {
        int u = (t >= off) ? s[t - off] : 0;
        __syncthreads();
        s[t] += u;
        __syncthreads();
    }
    if (t < NB) bbase[t] = s[t] - v;
    if (t == 0) rowptr[NN] = NE;
}

// ---- phase 3: per-bucket CSR build, LDS-staged, 1024 threads ----
__global__ __launch_bounds__(1024) void k_csr(const int* __restrict__ bcursor, const int* __restrict__ bbase,
                                              const unsigned int* __restrict__ packed,
                                              int* __restrict__ rowptr, float* __restrict__ dis,
                                              int* __restrict__ csr) {
    __shared__ unsigned int ent[CAP];   // 80 KB
    __shared__ int hist[512], cur[512], ps[512];
    int b = blockIdx.x;
    int t = threadIdx.x;
    int cnt = bcursor[b];
    int cbase = bbase[b];
    int node0 = b << 9;
    int nn = min(512, NN - node0);
    if (t < 512) hist[t] = 0;
    __syncthreads();
    const unsigned int* pk = packed + (size_t)b * CAP;
    for (int l = t; l < cnt; l += 1024) {
        unsigned int e = pk[l];
        ent[l] = e;
        atomicAdd(&hist[e >> 17], 1);
    }
    __syncthreads();
    if (t < 512) ps[t] = hist[t];
    __syncthreads();
    for (int off = 1; off < 512; off <<= 1) {
        int u = (t >= off && t < 512) ? ps[t - off] : 0;
        __syncthreads();
        if (t < 512) ps[t] += u;
        __syncthreads();
    }
    if (t < 512) {
        int excl = ps[t] - hist[t];
        cur[t] = excl;
        if (t < nn) {
            rowptr[node0 + t] = cbase + excl;
            dis[node0 + t] = rsqrtf((float)hist[t] + 1.0f);
        }
    }
    __syncthreads();
    for (int l = t; l < cnt; l += 1024) {
        unsigned int e = ent[l];
        int pos = atomicAdd(&cur[e >> 17], 1);
        csr[cbase + pos] = (int)(e & 0x1FFFF);
    }
}

// ---- y0 = fp8( dis * (x @ W) ); row/thread, W in LDS (broadcast reads),
//      x double-buffered float4 slabs ----
__global__ __launch_bounds__(128) void k_xw(const float* __restrict__ x, const float* __restrict__ W,
                                            const float* __restrict__ dis, unsigned char* __restrict__ y0) {
    __shared__ float Wl[ICH * OCH];  // 20 KB
    int t = threadIdx.x;
    {
        const float4* W4 = (const float4*)W;
        float4* Wl4 = (float4*)Wl;
#pragma unroll
        for (int i = 0; i < 10; ++i) Wl4[t + 128 * i] = W4[t + 128 * i];
    }
    __syncthreads();
    int row = blockIdx.x * 128 + t;
    if (row >= NN) return;
    const float4* xr = (const float4*)(x + (size_t)row * ICH);
    float acc[OCH];
#pragma unroll
    for (int c = 0; c < OCH; ++c) acc[c] = 0.f;
    float4 xa[8];
#pragma unroll
    for (int i = 0; i < 8; ++i) xa[i] = xr[i];
    for (int s = 0; s < 4; ++s) {
        float4 xb[8];
        if (s < 3) {
#pragma unroll
            for (int i = 0; i < 8; ++i) xb[i] = xr[8 * (s + 1) + i];
        }
#pragma unroll
        for (int i = 0; i < 8; ++i) {
            float4 xv = xa[i];
            const float* wr = Wl + (size_t)(s * 32 + 4 * i) * OCH;  // loop-uniform -> LDS broadcast
#pragma unroll
            for (int c = 0; c < OCH; ++c) acc[c] += xv.x * wr[c];
#pragma unroll
            for (int c = 0; c < OCH; ++c) acc[c] += xv.y * wr[OCH + c];
#pragma unroll
            for (int c = 0; c < OCH; ++c) acc[c] += xv.z * wr[2 * OCH + c];
#pragma unroll
            for (int c = 0; c < OCH; ++c) acc[c] += xv.w * wr[3 * OCH + c];
        }
        if (s < 3) {
#pragma unroll
            for (int i = 0; i < 8; ++i) xa[i] = xb[i];
        }
    }
    float d = dis[row];
#pragma unroll
    for (int c = 0; c < OCH; ++c) acc[c] *= d;
    uint2* yr = (uint2*)(y0 + (size_t)row * YSTRIDE);
#pragma unroll
    for (int q = 0; q < 5; ++q) yr[q] = pack_fp8x8(acc + 8 * q);
}

// ---- hop 1: y1[i] = fp8( dis[i]^2 * (y0[i] + sum_in y0[src]) )
//      5 lanes/node x 8B fp8 loads (1 line/neighbor), unroll 8 ----
__global__ __launch_bounds__(256) void k_hop1(const int* __restrict__ rowptr, const int* __restrict__ csr,
                                              const float* __restrict__ dis, const unsigned char* __restrict__ y0,
                                              unsigned char* __restrict__ y1) {
    int g = blockIdx.x * 256 + threadIdx.x;
    if (g >= NN * 5) return;
    int i = g / 5, q = g - 5 * i;
    const uint2* base = (const uint2*)y0;  // 8 uint2 per 64 B row
    float acc[8];
#pragma unroll
    for (int j = 0; j < 8; ++j) acc[j] = 0.f;
    acc_fp8x8(base[(size_t)i * 8 + q], acc);
    int kb = rowptr[i], ke = rowptr[i + 1];
    int k = kb;
    for (; k + 8 <= ke; k += 8) {
        int s0 = csr[k], s1 = csr[k + 1], s2 = csr[k + 2], s3 = csr[k + 3];
        int s4 = csr[k + 4], s5 = csr[k + 5], s6 = csr[k + 6], s7 = csr[k + 7];
        uint2 v0 = base[(size_t)s0 * 8 + q];
        uint2 v1 = base[(size_t)s1 * 8 + q];
        uint2 v2 = base[(size_t)s2 * 8 + q];
        uint2 v3 = base[(size_t)s3 * 8 + q];
        uint2 v4 = base[(size_t)s4 * 8 + q];
        uint2 v5 = base[(size_t)s5 * 8 + q];
        uint2 v6 = base[(size_t)s6 * 8 + q];
        uint2 v7 = base[(size_t)s7 * 8 + q];
        acc_fp8x8(v0, acc); acc_fp8x8(v1, acc); acc_fp8x8(v2, acc); acc_fp8x8(v3, acc);
        acc_fp8x8(v4, acc); acc_fp8x8(v5, acc); acc_fp8x8(v6, acc); acc_fp8x8(v7, acc);
    }
    for (; k < ke; ++k) {
        int s = csr[k];
        acc_fp8x8(base[(size_t)s * 8 + q], acc);
    }
    float d = dis[i], d2 = d * d;
#pragma unroll
    for (int j = 0; j < 8; ++j) acc[j] *= d2;
    ((uint2*)y1)[(size_t)i * 8 + q] = pack_fp8x8(acc);
}

// ---- hop 2 gather + bias + log_softmax, fused; 64 nodes/block, 5 lanes/node ----
__global__ __launch_bounds__(320) void k_hop2f(const int* __restrict__ rowptr, const int* __restrict__ csr,
                                               const float* __restrict__ dis, const unsigned char* __restrict__ y1,
                                               const float* __restrict__ b, float* __restrict__ out) {
    __shared__ float red[64][5];
    int tid = threadIdx.x;
    int lg = tid / 5;
    int q = tid - 5 * lg;
    int g = blockIdx.x * 64 + lg;
    bool active = (g < NN);
    float l[8];
    if (active) {
        const uint2* base = (const uint2*)y1;
        float acc[8];
#pragma unroll
        for (int j = 0; j < 8; ++j) acc[j] = 0.f;
        acc_fp8x8(base[(size_t)g * 8 + q], acc);
        int kb = rowptr[g], ke = rowptr[g + 1];
        int k = kb;
        for (; k + 8 <= ke; k += 8) {
            int s0 = csr[k], s1 = csr[k + 1], s2 = csr[k + 2], s3 = csr[k + 3];
            int s4 = csr[k + 4], s5 = csr[k + 5], s6 = csr[k + 6], s7 = csr[k + 7];
            uint2 v0 = base[(size_t)s0 * 8 + q];
            uint2 v1 = base[(size_t)s1 * 8 + q];
            uint2 v2 = base[(size_t)s2 * 8 + q];
            uint2 v3 = base[(size_t)s3 * 8 + q];
            uint2 v4 = base[(size_t)s4 * 8 + q];
            uint2 v5 = base[(size_t)s5 * 8 + q];
            uint2 v6 = base[(size_t)s6 * 8 + q];
            uint2 v7 = base[(size_t)s7 * 8 + q];
            acc_fp8x8(v0, acc); acc_fp8x8(v1, acc); acc_fp8x8(v2, acc); acc_fp8x8(v3, acc);
            acc_fp8x8(v4, acc); acc_fp8x8(v5, acc); acc_fp8x8(v6, acc); acc_fp8x8(v7, acc);
        }
        for (; k < ke; ++k) {
            int s = csr[k];
            acc_fp8x8(base[(size_t)s * 8 + q], acc);
        }
        float d = dis[g];
#pragma unroll
        for (int j = 0; j < 8; ++j) l[j] = d * acc[j] + b[8 * q + j];
    } else {
#pragma unroll
        for (int j = 0; j < 8; ++j) l[j] = -1e30f;
    }
    float m8 = l[0];
#pragma unroll
    for (int j = 1; j < 8; ++j) m8 = fmaxf(m8, l[j]);
    red[lg][q] = m8;
    __syncthreads();
    float gm = red[lg][0];
#pragma unroll
    for (int j = 1; j < 5; ++j) gm = fmaxf(gm, red[lg][j]);
    __syncthreads();
    float s8 = 0.f;
#pragma unroll
    for (int j = 0; j < 8; ++j) s8 += __expf(l[j] - gm);
    red[lg][q] = s8;
    __syncthreads();
    float gs = red[lg][0];
#pragma unroll
    for (int j = 1; j < 5; ++j) gs += red[lg][j];
    float ls = __logf(gs) + gm;
    if (active) {
        float4* orow = (float4*)(out + (size_t)g * OCH + 8 * q);
        orow[0] = make_float4(l[0] - ls, l[1] - ls, l[2] - ls, l[3] - ls);
        orow[1] = make_float4(l[4] - ls, l[5] - ls, l[6] - ls, l[7] - ls);
    }
}

extern "C" void kernel_launch(void* const* d_in, const int* in_sizes, int n_in,
                              void* d_out, int out_size, void* d_ws, size_t ws_size,
                              hipStream_t stream) {
    const float* x  = (const float*)d_in[0];
    const int*   ei = (const int*)d_in[1];   // (2, E) int32; [0]=src, [1]=dst
    const float* W  = (const float*)d_in[2];
    const float* b  = (const float*)d_in[3];
    float* out = (float*)d_out;

    char* ws = (char*)d_ws;
    int*           bcursor = (int*)(ws + 0);          // NB ints
    int*           bbase   = (int*)(ws + 1024);       // NB ints
    int*           rowptr  = (int*)(ws + 2048);       // NN+1 ints
    float*         dis     = (float*)(ws + 402432);   // NN floats
    unsigned int*  packed  = (unsigned int*)(ws + 802432);  // NB*CAP = 16.06 MB (dead after k_csr)
    unsigned char* y0      = (unsigned char*)(ws + 802432); // aliases packed, NN*64 B = 6.4 MB
    unsigned char* y1      = (unsigned char*)(ws + 7202432);// aliases packed, 6.4 MB
    int*           csr     = (int*)(ws + 16858752);   // NE ints (12.8 MB)

    hipMemsetAsync(bcursor, 0, NB * sizeof(int), stream);
    k_bin<<<NBIN, 256, 0, stream>>>(ei, bcursor, packed);
    k_bscan<<<1, 256, 0, stream>>>(bcursor, bbase, rowptr);
    k_csr<<<NB, 1024, 0, stream>>>(bcursor, bbase, packed, rowptr, dis, csr);
    k_xw<<<(NN + 127) / 128, 128, 0, stream>>>(x, W, dis, y0);
    k_hop1<<<(NN * 5 + 255) / 256, 256, 0, stream>>>(rowptr, csr, dis, y0, y1);
    k_hop2f<<<(NN + 63) / 64, 320, 0, stream>>>(rowptr, csr, dis, y1, b, out);
}

// Round 10
// 265.059 us; speedup vs baseline: 4.8025x; 4.8025x over previous
//
#include <hip/hip_runtime.h>
#include <hip/hip_fp16.h>
#include <math.h>

#define NN 100000
#define ICH 128
#define OCH 40
#define NE 3200000
#define NB 196                         // buckets of 512 nodes: bucket = dst >> 9
#define CAP 20480                      // per-bucket capacity (mean 16384, sigma ~128)
#define TILE 4096
#define NBIN ((NE + TILE - 1) / TILE)  // 782
#define YSTRIDE 64                     // fp8 row: 40 B data + 24 B pad = exactly 1 cache line

typedef __attribute__((ext_vector_type(2))) float floatx2;

// decode 8 fp8 (uint2) -> acc[8] +=
__device__ __forceinline__ void acc_fp8x8(const uint2 u, float* acc) {
    floatx2 p0 = __builtin_amdgcn_cvt_pk_f32_fp8((int)u.x, false);
    floatx2 p1 = __builtin_amdgcn_cvt_pk_f32_fp8((int)u.x, true);
    floatx2 p2 = __builtin_amdgcn_cvt_pk_f32_fp8((int)u.y, false);
    floatx2 p3 = __builtin_amdgcn_cvt_pk_f32_fp8((int)u.y, true);
    acc[0] += p0.x; acc[1] += p0.y; acc[2] += p1.x; acc[3] += p1.y;
    acc[4] += p2.x; acc[5] += p2.y; acc[6] += p3.x; acc[7] += p3.y;
}

// encode 8 f32 -> uint2 of fp8
__device__ __forceinline__ uint2 pack_fp8x8(const float* v) {
    int lo = 0, hi = 0;
    lo = __builtin_amdgcn_cvt_pk_fp8_f32(v[0], v[1], lo, false);
    lo = __builtin_amdgcn_cvt_pk_fp8_f32(v[2], v[3], lo, true);
    hi = __builtin_amdgcn_cvt_pk_fp8_f32(v[4], v[5], hi, false);
    hi = __builtin_amdgcn_cvt_pk_fp8_f32(v[6], v[7], hi, true);
    return make_uint2((unsigned int)lo, (unsigned int)hi);
}

// ---- phase 1: bin edges by dst-bucket; dense packed writes per bucket ----
__global__ __launch_bounds__(256) void k_bin(const int* __restrict__ ei, int* __restrict__ bcursor,
                                             unsigned int* __restrict__ packed) {
    __shared__ unsigned int entries[TILE];
    __shared__ unsigned char bid[TILE];
    __shared__ int hist[256], base[256], gbase[256], cur[256];
    int t = threadIdx.x;
    int tile0 = blockIdx.x * TILE;
    int tcnt = min(TILE, NE - tile0);
    hist[t] = 0;
    __syncthreads();
    int src[16], dst[16];
#pragma unroll
    for (int i = 0; i < 16; ++i) {
        int l = t + i * 256;
        if (l < tcnt) {
            int e = tile0 + l;
            src[i] = ei[e];
            dst[i] = ei[NE + e];
            atomicAdd(&hist[dst[i] >> 9], 1);
        } else dst[i] = -1;
    }
    __syncthreads();
    int own = hist[t];
    base[t] = own;
    __syncthreads();
    for (int off = 1; off < 256; off <<= 1) {
        int v = (t >= off) ? base[t - off] : 0;
        __syncthreads();
        base[t] += v;
        __syncthreads();
    }
    int excl = base[t] - own;
    __syncthreads();
    base[t] = excl;
    cur[t] = excl;
    if (t < NB && own > 0) gbase[t] = atomicAdd(&bcursor[t], own);
    __syncthreads();
#pragma unroll
    for (int i = 0; i < 16; ++i) {
        if (dst[i] >= 0) {
            int b = dst[i] >> 9;
            int pos = atomicAdd(&cur[b], 1);
            entries[pos] = ((unsigned int)(dst[i] & 511) << 17) | (unsigned int)src[i];
            bid[pos] = (unsigned char)b;
        }
    }
    __syncthreads();
    for (int l = t; l < tcnt; l += 256) {
        int b = bid[l];
        packed[(size_t)b * CAP + gbase[b] + (l - base[b])] = entries[l];
    }
}

// ---- phase 2: scan bucket counts -> bucket CSR bases ----
__global__ __launch_bounds__(256) void k_bscan(const int* __restrict__ bcursor, int* __restrict__ bbase,
                                               int* __restrict__ rowptr) {
    __shared__ int s[256];
    int t = threadIdx.x;
    int v = (t < NB) ? bcursor[t] : 0;
    s[t] = v;
    __syncthreads();
    for (int off = 1; off < 256; off <<= 1) {
        int u = (t >= off) ? s[t - off] : 0;
        __syncthreads();
        s[t] += u;
        __syncthreads();
    }
    if (t < NB) bbase[t] = s[t] - v;
    if (t == 0) rowptr[NN] = NE;
}

// ---- phase 3: per-bucket CSR build, LDS-staged, 1024 threads ----
__global__ __launch_bounds__(1024) void k_csr(const int* __restrict__ bcursor, const int* __restrict__ bbase,
                                              const unsigned int* __restrict__ packed,
                                              int* __restrict__ rowptr, float* __restrict__ dis,
                                              int* __restrict__ csr) {
    __shared__ unsigned int ent[CAP];   // 80 KB
    __shared__ int hist[512], cur[512], ps[512];
    int b = blockIdx.x;
    int t = threadIdx.x;
    int cnt = bcursor[b];
    int cbase = bbase[b];
    int node0 = b << 9;
    int nn = min(512, NN - node0);
    if (t < 512) hist[t] = 0;
    __syncthreads();
    const unsigned int* pk = packed + (size_t)b * CAP;
    for (int l = t; l < cnt; l += 1024) {
        unsigned int e = pk[l];
        ent[l] = e;
        atomicAdd(&hist[e >> 17], 1);
    }
    __syncthreads();
    if (t < 512) ps[t] = hist[t];
    __syncthreads();
    for (int off = 1; off < 512; off <<= 1) {
        int u = (t >= off && t < 512) ? ps[t - off] : 0;
        __syncthreads();
        if (t < 512) ps[t] += u;
        __syncthreads();
    }
    if (t < 512) {
        int excl = ps[t] - hist[t];
        cur[t] = excl;
        if (t < nn) {
            rowptr[node0 + t] = cbase + excl;
            dis[node0 + t] = rsqrtf((float)hist[t] + 1.0f);
        }
    }
    __syncthreads();
    for (int l = t; l < cnt; l += 1024) {
        unsigned int e = ent[l];
        int pos = atomicAdd(&cur[e >> 17], 1);
        csr[cbase + pos] = (int)(e & 0x1FFFF);
    }
}

// ---- y0 = fp8( dis * (x @ W) ); R6 structure, W staged in LDS (broadcast reads) ----
__global__ __launch_bounds__(256) void k_xw(const float* __restrict__ x, const float* __restrict__ W,
                                            const float* __restrict__ dis, unsigned char* __restrict__ y0) {
    __shared__ float Wl[ICH * OCH];  // 20 KB
    int t = threadIdx.x;
    {
        const float4* W4 = (const float4*)W;
        float4* Wl4 = (float4*)Wl;
#pragma unroll
        for (int i = 0; i < 5; ++i) Wl4[t + 256 * i] = W4[t + 256 * i];  // 1280 float4s
    }
    __syncthreads();
    int row = blockIdx.x * 256 + t;
    if (row >= NN) return;
    const float4* xr = (const float4*)(x + (size_t)row * ICH);
    float acc[OCH];
#pragma unroll
    for (int c = 0; c < OCH; ++c) acc[c] = 0.f;
    for (int k4 = 0; k4 < ICH / 4; ++k4) {
        float4 xv = xr[k4];
        const float* wr = Wl + (size_t)(4 * k4) * OCH;  // loop-uniform -> LDS broadcast
#pragma unroll
        for (int c = 0; c < OCH; ++c) acc[c] += xv.x * wr[c];
#pragma unroll
        for (int c = 0; c < OCH; ++c) acc[c] += xv.y * wr[OCH + c];
#pragma unroll
        for (int c = 0; c < OCH; ++c) acc[c] += xv.z * wr[2 * OCH + c];
#pragma unroll
        for (int c = 0; c < OCH; ++c) acc[c] += xv.w * wr[3 * OCH + c];
    }
    float d = dis[row];
#pragma unroll
    for (int c = 0; c < OCH; ++c) acc[c] *= d;
    uint2* yr = (uint2*)(y0 + (size_t)row * YSTRIDE);
#pragma unroll
    for (int q = 0; q < 5; ++q) yr[q] = pack_fp8x8(acc + 8 * q);
}

// ---- hop 1: y1[i] = fp8( dis[i]^2 * (y0[i] + sum_in y0[src]) )
//      5 lanes/node x 8B fp8 loads (1 line/neighbor), unroll 8 ----
__global__ __launch_bounds__(256) void k_hop1(const int* __restrict__ rowptr, const int* __restrict__ csr,
                                              const float* __restrict__ dis, const unsigned char* __restrict__ y0,
                                              unsigned char* __restrict__ y1) {
    int g = blockIdx.x * 256 + threadIdx.x;
    if (g >= NN * 5) return;
    int i = g / 5, q = g - 5 * i;
    const uint2* base = (const uint2*)y0;  // 8 uint2 per 64 B row
    float acc[8];
#pragma unroll
    for (int j = 0; j < 8; ++j) acc[j] = 0.f;
    acc_fp8x8(base[(size_t)i * 8 + q], acc);
    int kb = rowptr[i], ke = rowptr[i + 1];
    int k = kb;
    for (; k + 8 <= ke; k += 8) {
        int s0 = csr[k], s1 = csr[k + 1], s2 = csr[k + 2], s3 = csr[k + 3];
        int s4 = csr[k + 4], s5 = csr[k + 5], s6 = csr[k + 6], s7 = csr[k + 7];
        uint2 v0 = base[(size_t)s0 * 8 + q];
        uint2 v1 = base[(size_t)s1 * 8 + q];
        uint2 v2 = base[(size_t)s2 * 8 + q];
        uint2 v3 = base[(size_t)s3 * 8 + q];
        uint2 v4 = base[(size_t)s4 * 8 + q];
        uint2 v5 = base[(size_t)s5 * 8 + q];
        uint2 v6 = base[(size_t)s6 * 8 + q];
        uint2 v7 = base[(size_t)s7 * 8 + q];
        acc_fp8x8(v0, acc); acc_fp8x8(v1, acc); acc_fp8x8(v2, acc); acc_fp8x8(v3, acc);
        acc_fp8x8(v4, acc); acc_fp8x8(v5, acc); acc_fp8x8(v6, acc); acc_fp8x8(v7, acc);
    }
    for (; k < ke; ++k) {
        int s = csr[k];
        acc_fp8x8(base[(size_t)s * 8 + q], acc);
    }
    float d = dis[i], d2 = d * d;
#pragma unroll
    for (int j = 0; j < 8; ++j) acc[j] *= d2;
    ((uint2*)y1)[(size_t)i * 8 + q] = pack_fp8x8(acc);
}

// ---- hop 2 gather + bias + log_softmax, fused; 64 nodes/block, 5 lanes/node ----
__global__ __launch_bounds__(320) void k_hop2f(const int* __restrict__ rowptr, const int* __restrict__ csr,
                                               const float* __restrict__ dis, const unsigned char* __restrict__ y1,
                                               const float* __restrict__ b, float* __restrict__ out) {
    __shared__ float red[64][5];
    int tid = threadIdx.x;
    int lg = tid / 5;
    int q = tid - 5 * lg;
    int g = blockIdx.x * 64 + lg;
    bool active = (g < NN);
    float l[8];
    if (active) {
        const uint2* base = (const uint2*)y1;
        float acc[8];
#pragma unroll
        for (int j = 0; j < 8; ++j) acc[j] = 0.f;
        acc_fp8x8(base[(size_t)g * 8 + q], acc);
        int kb = rowptr[g], ke = rowptr[g + 1];
        int k = kb;
        for (; k + 8 <= ke; k += 8) {
            int s0 = csr[k], s1 = csr[k + 1], s2 = csr[k + 2], s3 = csr[k + 3];
            int s4 = csr[k + 4], s5 = csr[k + 5], s6 = csr[k + 6], s7 = csr[k + 7];
            uint2 v0 = base[(size_t)s0 * 8 + q];
            uint2 v1 = base[(size_t)s1 * 8 + q];
            uint2 v2 = base[(size_t)s2 * 8 + q];
            uint2 v3 = base[(size_t)s3 * 8 + q];
            uint2 v4 = base[(size_t)s4 * 8 + q];
            uint2 v5 = base[(size_t)s5 * 8 + q];
            uint2 v6 = base[(size_t)s6 * 8 + q];
            uint2 v7 = base[(size_t)s7 * 8 + q];
            acc_fp8x8(v0, acc); acc_fp8x8(v1, acc); acc_fp8x8(v2, acc); acc_fp8x8(v3, acc);
            acc_fp8x8(v4, acc); acc_fp8x8(v5, acc); acc_fp8x8(v6, acc); acc_fp8x8(v7, acc);
        }
        for (; k < ke; ++k) {
            int s = csr[k];
            acc_fp8x8(base[(size_t)s * 8 + q], acc);
        }
        float d = dis[g];
#pragma unroll
        for (int j = 0; j < 8; ++j) l[j] = d * acc[j] + b[8 * q + j];
    } else {
#pragma unroll
        for (int j = 0; j < 8; ++j) l[j] = -1e30f;
    }
    float m8 = l[0];
#pragma unroll
    for (int j = 1; j < 8; ++j) m8 = fmaxf(m8, l[j]);
    red[lg][q] = m8;
    __syncthreads();
    float gm = red[lg][0];
#pragma unroll
    for (int j = 1; j < 5; ++j) gm = fmaxf(gm, red[lg][j]);
    __syncthreads();
    float s8 = 0.f;
#pragma unroll
    for (int j = 0; j < 8; ++j) s8 += __expf(l[j] - gm);
    red[lg][q] = s8;
    __syncthreads();
    float gs = red[lg][0];
#pragma unroll
    for (int j = 1; j < 5; ++j) gs += red[lg][j];
    float ls = __logf(gs) + gm;
    if (active) {
        float4* orow = (float4*)(out + (size_t)g * OCH + 8 * q);
        orow[0] = make_float4(l[0] - ls, l[1] - ls, l[2] - ls, l[3] - ls);
        orow[1] = make_float4(l[4] - ls, l[5] - ls, l[6] - ls, l[7] - ls);
    }
}

extern "C" void kernel_launch(void* const* d_in, const int* in_sizes, int n_in,
                              void* d_out, int out_size, void* d_ws, size_t ws_size,
                              hipStream_t stream) {
    const float* x  = (const float*)d_in[0];
    const int*   ei = (const int*)d_in[1];   // (2, E) int32; [0]=src, [1]=dst
    const float* W  = (const float*)d_in[2];
    const float* b  = (const float*)d_in[3];
    float* out = (float*)d_out;

    char* ws = (char*)d_ws;
    int*           bcursor = (int*)(ws + 0);          // NB ints
    int*           bbase   = (int*)(ws + 1024);       // NB ints
    int*           rowptr  = (int*)(ws + 2048);       // NN+1 ints
    float*         dis     = (float*)(ws + 402432);   // NN floats
    unsigned int*  packed  = (unsigned int*)(ws + 802432);  // NB*CAP = 16.06 MB (dead after k_csr)
    unsigned char* y0      = (unsigned char*)(ws + 802432); // aliases packed, NN*64 B = 6.4 MB
    unsigned char* y1      = (unsigned char*)(ws + 7202432);// aliases packed, 6.4 MB
    int*           csr     = (int*)(ws + 16858752);   // NE ints (12.8 MB)

    hipMemsetAsync(bcursor, 0, NB * sizeof(int), stream);
    k_bin<<<NBIN, 256, 0, stream>>>(ei, bcursor, packed);
    k_bscan<<<1, 256, 0, stream>>>(bcursor, bbase, rowptr);
    k_csr<<<NB, 1024, 0, stream>>>(bcursor, bbase, packed, rowptr, dis, csr);
    k_xw<<<(NN + 255) / 256, 256, 0, stream>>>(x, W, dis, y0);
    k_hop1<<<(NN * 5 + 255) / 256, 256, 0, stream>>>(rowptr, csr, dis, y0, y1);
    k_hop2f<<<(NN + 63) / 64, 320, 0, stream>>>(rowptr, csr, dis, y1, b, out);
}